// Round 2
// baseline (413.198 us; speedup 1.0000x reference)
//
#include <hip/hip_runtime.h>
#include <math.h>

#define NL 7

// One block per (b, i): 4 waves, wave dd handles neighbor offset
// dj = (dd<2 ? dd-2 : dd-1) in {-2,-1,+1,+2}. Each thread = one (ai,aj)
// position of its tile, evolving 8 channels through the conv stack.
// Block then writes its 64 full output rows (8 c x 8 ai x 1024 cols).
__global__ __launch_bounds__(256) void fused_kernel(
    const float* __restrict__ pw,      // (64, 1024, 1024)
    const float* __restrict__ conv_w,  // (7, 8, 8, 1, 3)
    const float* __restrict__ conv_b,  // (7, 8)
    const float* __restrict__ prelu_a, // (7,)
    float* __restrict__ out)           // (64, 1024, 1024)
{
    __shared__ float wts[NL][8][8][3];
    __shared__ float bs[NL][8];
    __shared__ float al[NL];
    __shared__ float cur[4][8][64];    // [dd][c][ai*8+aj]; becomes we after gate
    __shared__ float rowinv[64];       // [c*8+ai]

    const int b = blockIdx.x >> 7;
    const int i = blockIdx.x & 127;
    const int t = threadIdx.x;
    const int dd = t >> 6;             // wave id = tile slot
    const int lane = t & 63;
    const int ai = lane >> 3, aj = lane & 7;
    const int dj = (dd < 2) ? dd - 2 : dd - 1;   // -2,-1,+1,+2
    const int j = i + dj;
    const bool valid = (j >= 0) && (j < 128);

    // stage weights
    for (int p = t; p < NL * 8 * 8 * 3; p += 256) ((float*)wts)[p] = conv_w[p];
    for (int p = t; p < NL * 8; p += 256)         ((float*)bs)[p]  = conv_b[p];
    if (t < NL) al[t] = prelu_a[t];

    // load x tile (zeros for invalid neighbor)
    float x[8], h[8];
    const float* base = pw + (((size_t)(b * 8)) << 20)
                           + (size_t)(i * 8 + ai) * 1024
                           + (size_t)((valid ? j : 0) * 8 + aj);
    #pragma unroll
    for (int c = 0; c < 8; ++c) {
        x[c] = valid ? base[((size_t)c) << 20] : 0.f;
        h[c] = x[c];
        cur[dd][c][lane] = x[c];
    }
    __syncthreads();

    // 7-layer conv(1x3, pad 1 along aj) + bias + PReLU + residual
    for (int l = 0; l < NL; ++l) {
        float v0[8], v2[8];
        #pragma unroll
        for (int ci = 0; ci < 8; ++ci) {
            v0[ci] = (aj > 0) ? cur[dd][ci][lane - 1] : 0.f;
            v2[ci] = (aj < 7) ? cur[dd][ci][lane + 1] : 0.f;
        }
        const float a = al[l];
        float nxt[8];
        #pragma unroll
        for (int co = 0; co < 8; ++co) {
            float acc = bs[l][co];
            #pragma unroll
            for (int ci = 0; ci < 8; ++ci) {
                acc += wts[l][co][ci][0] * v0[ci]
                     + wts[l][co][ci][1] * h[ci]
                     + wts[l][co][ci][2] * v2[ci];
            }
            float y = (acc >= 0.f) ? acc : a * acc;
            nxt[co] = y + h[co];
        }
        __syncthreads();
        #pragma unroll
        for (int co = 0; co < 8; ++co) {
            h[co] = nxt[co];
            cur[dd][co][lane] = nxt[co];
        }
        __syncthreads();
    }

    // gate -> we, stored in place in cur
    #pragma unroll
    for (int c = 0; c < 8; ++c) {
        float sg = 1.f / (1.f + __expf(-h[c]));
        float s = x[c] - sg;
        s = (s > 0.f) ? s : 0.f;
        float we = (valid && ai != aj) ? expm1f(s) : 0.f;
        cur[dd][c][lane] = we;
    }
    __syncthreads();

    // row sums (rows = (c, ai)), done by first 64 threads
    if (t < 64) {
        const int c = t >> 3, aii = t & 7;
        float s = 0.f;
        #pragma unroll
        for (int d2 = 0; d2 < 4; ++d2)
            #pragma unroll
            for (int a2 = 0; a2 < 8; ++a2)
                s += cur[d2][c][aii * 8 + a2];
        rowinv[t] = 1.f / (s + 1e-5f);
    }
    __syncthreads();

    // write 64 full output rows, float4-coalesced
    const int row0 = t >> 6;           // 0..3
    const int l64  = t & 63;
    for (int g = 0; g < 16; ++g) {
        const int row = g * 4 + row0;  // 0..63 = c*8+ai
        const int c  = row >> 3;
        const int airow = row & 7;
        const float inv = rowinv[row];
        float4* rowp = (float4*)(out + ((((size_t)(b * 8 + c)) * 1024
                                         + (size_t)(i * 8 + airow)) << 10));
        #pragma unroll
        for (int k = 0; k < 4; ++k) {
            const int col4 = k * 64 + l64;   // float4 index in row, 0..255
            const int jc = col4 >> 1;        // j block of this float4
            const int djc = jc - i;
            float4 v = make_float4(0.f, 0.f, 0.f, 0.f);
            if (djc >= -2 && djc <= 2 && djc != 0) {
                const int d2 = (djc < 0) ? djc + 2 : djc + 1;
                const int off = airow * 8 + (col4 & 1) * 4;
                v.x = cur[d2][c][off + 0] * inv;
                v.y = cur[d2][c][off + 1] * inv;
                v.z = cur[d2][c][off + 2] * inv;
                v.w = cur[d2][c][off + 3] * inv;
            }
            rowp[col4] = v;
        }
    }
}

extern "C" void kernel_launch(void* const* d_in, const int* in_sizes, int n_in,
                              void* d_out, int out_size, void* d_ws, size_t ws_size,
                              hipStream_t stream) {
    const float* pw      = (const float*)d_in[0];
    const float* conv_w  = (const float*)d_in[1];
    const float* conv_b  = (const float*)d_in[2];
    const float* prelu_a = (const float*)d_in[3];
    // scalars d_in[4..6] (bsz=8, cross_range=2, agent_num=8) baked in.
    (void)d_ws; (void)ws_size;

    fused_kernel<<<8 * 128, 256, 0, stream>>>(pw, conv_w, conv_b, prelu_a,
                                              (float*)d_out);
}